// Round 1
// baseline (290.942 us; speedup 1.0000x reference)
//
#include <hip/hip_runtime.h>

// out[b,h,w,d,c] = in[b,h,w,d] * u[d,c],  u = beta^2 / rowsum(beta^2)
// in: [16,160,320,32] fp32 (26,214,400 elems), beta: [32,2] fp32,
// out: [16,160,320,32,2] fp32 (52,428,800 elems).
// Memory-bound: ~315 MB total traffic -> ~50 us roofline at 6.3 TB/s.

__global__ __launch_bounds__(256) void DS2_87582973100612_kernel(
    const float4* __restrict__ in4,
    const float*  __restrict__ beta,
    float4*       __restrict__ out4,
    int n4)
{
    const int gid    = blockIdx.x * blockDim.x + threadIdx.x;
    const int stride = gridDim.x * blockDim.x; // multiple of 8 -> d0 loop-invariant

    // Each thread always sees the same 4 consecutive d values.
    const int d0 = (4 * gid) & 31;
    float u0[4], u1[4];
#pragma unroll
    for (int k = 0; k < 4; ++k) {
        const int d = d0 + k;
        const float b0 = beta[2 * d];
        const float b1 = beta[2 * d + 1];
        const float s0 = b0 * b0;
        const float s1 = b1 * b1;
        const float inv = 1.0f / (s0 + s1);
        u0[k] = s0 * inv;
        u1[k] = s1 * inv;
    }

    for (int i = gid; i < n4; i += stride) {
        const float4 x = in4[i];
        float4 y0, y1;
        y0.x = x.x * u0[0];  y0.y = x.x * u1[0];
        y0.z = x.y * u0[1];  y0.w = x.y * u1[1];
        y1.x = x.z * u0[2];  y1.y = x.z * u1[2];
        y1.z = x.w * u0[3];  y1.w = x.w * u1[3];
        out4[2 * i]     = y0;
        out4[2 * i + 1] = y1;
    }
}

extern "C" void kernel_launch(void* const* d_in, const int* in_sizes, int n_in,
                              void* d_out, int out_size, void* d_ws, size_t ws_size,
                              hipStream_t stream) {
    const float* in   = (const float*)d_in[0];
    const float* beta = (const float*)d_in[1];
    float* out        = (float*)d_out;

    const int n  = in_sizes[0];     // 26,214,400
    const int n4 = n / 4;           // input is divisible by 4

    const int block = 256;
    const int grid  = 2048;         // grid-stride; stride = 524,288 threads (mult of 8)

    DS2_87582973100612_kernel<<<grid, block, 0, stream>>>(
        (const float4*)in, beta, (float4*)out, n4);
}

// Round 2
// 281.943 us; speedup vs baseline: 1.0319x; 1.0319x over previous
//
#include <hip/hip_runtime.h>

// out[b,h,w,d,c] = in[b,h,w,d] * u[d,c],  u = beta^2 / rowsum(beta^2)
// in: [16,160,320,32] fp32 (26,214,400), beta: [32,2], out: 2x in (52,428,800).
// Memory-bound: ~315 MB traffic -> ~50 us roofline at 6.3 TB/s.
//
// Output-centric: thread o produces output float4 o (16B coalesced store)
// from input float2 o (8B coalesced load). R1's input-centric version had
// stride-2 float4 stores across lanes (each store touched 2x the lines).

__global__ __launch_bounds__(256) void DS2_87582973100612_kernel(
    const float2* __restrict__ in2,
    const float*  __restrict__ beta,
    float4*       __restrict__ out4,
    int n_out4)
{
    const int gid    = blockIdx.x * blockDim.x + threadIdx.x;
    const int stride = gridDim.x * blockDim.x; // multiple of 16 -> d0 loop-invariant

    // Output float4 o covers (d0, d1=d0+1) with d0 = (2*o) & 31 (even).
    const int d0 = (2 * gid) & 31;
    const int d1 = d0 + 1;

    const float a0 = beta[2 * d0], a1 = beta[2 * d0 + 1];
    const float b0 = beta[2 * d1], b1 = beta[2 * d1 + 1];
    const float sa0 = a0 * a0, sa1 = a1 * a1;
    const float sb0 = b0 * b0, sb1 = b1 * b1;
    const float inva = 1.0f / (sa0 + sa1);
    const float invb = 1.0f / (sb0 + sb1);
    const float u00 = sa0 * inva, u01 = sa1 * inva; // u[d0, 0], u[d0, 1]
    const float u10 = sb0 * invb, u11 = sb1 * invb; // u[d1, 0], u[d1, 1]

    for (int o = gid; o < n_out4; o += stride) {
        const float2 x = in2[o];
        float4 y;
        y.x = x.x * u00;
        y.y = x.x * u01;
        y.z = x.y * u10;
        y.w = x.y * u11;
        out4[o] = y;
    }
}

extern "C" void kernel_launch(void* const* d_in, const int* in_sizes, int n_in,
                              void* d_out, int out_size, void* d_ws, size_t ws_size,
                              hipStream_t stream) {
    const float* in   = (const float*)d_in[0];
    const float* beta = (const float*)d_in[1];
    float* out        = (float*)d_out;

    const int n_out4 = out_size / 4;  // 13,107,200

    const int block = 256;
    const int grid  = 4096;           // 1,048,576 threads; stride mult of 16

    DS2_87582973100612_kernel<<<grid, block, 0, stream>>>(
        (const float2*)in, beta, (float4*)out, n_out4);
}